// Round 7
// baseline (50.342 us; speedup 1.0000x reference)
//
#include <hip/hip_runtime.h>
#include <stdint.h>

// B=1, N=2048, D=1024, h=16, e=64; chunks of 64 tokens -> 32 chunks/head
#define NTOK 2048
#define NCH 32

typedef __attribute__((ext_vector_type(8))) short bf16x8;
typedef __attribute__((ext_vector_type(8))) unsigned short ushort8v;
typedef __attribute__((ext_vector_type(4))) float f32x4;

__device__ __forceinline__ unsigned short f2bf(float f) {
  unsigned u = __float_as_uint(f);
  u += 0x7fffu + ((u >> 16) & 1u);   // RNE
  return (unsigned short)(u >> 16);
}
__device__ __forceinline__ float bf2f(unsigned short s) {
  return __uint_as_float(((unsigned)s) << 16);
}

// ---- fused input prep: x -> bf16 (blocks 0..2047), W -> Wt bf16 transposed (blocks 2048..5119) ----
__global__ __launch_bounds__(256) void k_prep_inputs(const float* __restrict__ x,
                                                     unsigned short* __restrict__ xb,
                                                     const float* __restrict__ W,
                                                     unsigned short* __restrict__ Wt) {
  int bid = blockIdx.x;
  if (bid < 2048) {
    int i = (bid * 256 + threadIdx.x) * 4;
    float4 v = *(const float4*)(x + i);
    ushort4 o = { f2bf(v.x), f2bf(v.y), f2bf(v.z), f2bf(v.w) };
    *(ushort4*)(xb + i) = o;
  } else {
    __shared__ float tile[32][33];
    int id = bid - 2048;            // 3072 blocks: bx in [0,96), by in [0,32)
    int bx = id % 96, by = id / 96;
    int tx = threadIdx.x & 31, ty = threadIdx.x >> 5;
    int c0 = bx * 32;
    int r0 = by * 32;
#pragma unroll
    for (int j = 0; j < 32; j += 8)
      tile[ty + j][tx] = W[(size_t)(r0 + ty + j) * 3072 + c0 + tx];
    __syncthreads();
#pragma unroll
    for (int j = 0; j < 32; j += 8)
      Wt[(size_t)(c0 + ty + j) * 1024 + r0 + tx] = f2bf(tile[tx][ty + j]);
  }
}

// ---- GEMM 2048x3072, 128x128 tile, 256 thr (4 waves of 64x64), BK=64 ----
// Depth-2 pipeline, COUNTED vmcnt(8) (never drains to 0 in the loop).
// 8 global_load_lds per thread per K-tile, uniform across waves.
// grid (24,16) = 384 blocks, LDS 64 KB -> 2 blocks/CU.
__global__ __launch_bounds__(256, 2) void k_gemm_fused(const unsigned short* __restrict__ xb,
                                                       const unsigned short* __restrict__ wt,
                                                       const float* __restrict__ bias,
                                                       unsigned short* __restrict__ qh,
                                                       unsigned short* __restrict__ kh,
                                                       unsigned short* __restrict__ kt,
                                                       unsigned short* __restrict__ vt) {
  __shared__ __align__(16) unsigned short As[2][128][64];    // 2 x 16 KB
  __shared__ __align__(16) unsigned short Bs[2][128][64];    // 2 x 16 KB
  const int t = threadIdx.x;           // 0..255
  const int lane = t & 63;
  const int wave = t >> 6;             // 0..3
  const int wr = wave >> 1;            // 0..1 (64-row block)
  const int wc = wave & 1;             // 0..1 (64-col block)
  const int rowBase = blockIdx.y * 128;
  const int colBase = blockIdx.x * 128;
  const int fr = lane & 15;
  const int khalf = lane >> 4;         // 0..3

  // staging: 2048 x 16B loads/tile = [A: 1024 | B: 1024], 8 uniform rounds of 256
  const unsigned short* g[8];
  char* l0[8];
#pragma unroll
  for (int r = 0; r < 8; ++r) {
    int s = t + r * 256;
    bool isA = s < 1024;
    int idx = isA ? s : (s - 1024);
    int row = idx >> 3;                // 0..127
    int slot = (idx & 7) ^ (row & 7);  // XOR swizzle (inverse on source)
    g[r] = isA ? (xb + (size_t)(rowBase + row) * 1024 + slot * 8)
               : (wt + (size_t)(colBase + row) * 1024 + slot * 8);
    l0[r] = (isA ? (char*)As : (char*)Bs) + idx * 16;
  }

#define STG(buf, kt0) do {                                                                \
    _Pragma("unroll")                                                                     \
    for (int r_ = 0; r_ < 8; ++r_)                                                        \
      __builtin_amdgcn_global_load_lds(                                                   \
          (const __attribute__((address_space(1))) void*)(g[r_] + (kt0) * 64),            \
          (__attribute__((address_space(3))) void*)(l0[r_] + (buf) * 16384),              \
          16, 0, 0);                                                                      \
  } while (0)

#define VMCNT8() asm volatile("s_waitcnt vmcnt(8)" ::: "memory")
#define VMCNT0() asm volatile("s_waitcnt vmcnt(0)" ::: "memory")
#define LGKM0()  asm volatile("s_waitcnt lgkmcnt(0)" ::: "memory")
#define BAR()    __builtin_amdgcn_s_barrier()

  f32x4 acc[4][4] = {};
  const int fs0 = khalf ^ (fr & 7);   // swizzled slot for ks=0; ks=1 is fs0^4

#define LOAD_FRAGS(cur, af, bff) do {                                                     \
    _Pragma("unroll")                                                                     \
    for (int m = 0; m < 4; ++m) {                                                         \
      const unsigned short* r = &As[cur][wr * 64 + m * 16 + fr][0];                       \
      af[m][0] = *(const bf16x8*)(r + fs0 * 8);                                           \
      af[m][1] = *(const bf16x8*)(r + (fs0 ^ 4) * 8);                                     \
    }                                                                                     \
    _Pragma("unroll")                                                                     \
    for (int n = 0; n < 4; ++n) {                                                         \
      const unsigned short* r = &Bs[cur][wc * 64 + n * 16 + fr][0];                       \
      bff[n][0] = *(const bf16x8*)(r + fs0 * 8);                                          \
      bff[n][1] = *(const bf16x8*)(r + (fs0 ^ 4) * 8);                                    \
    }                                                                                     \
  } while (0)

#define DO_MFMA(af, bff) do {                                                             \
    _Pragma("unroll")                                                                     \
    for (int m = 0; m < 4; ++m)                                                           \
      _Pragma("unroll")                                                                   \
      for (int n = 0; n < 4; ++n) {                                                       \
        acc[m][n] = __builtin_amdgcn_mfma_f32_16x16x32_bf16(af[m][0], bff[n][0], acc[m][n], 0, 0, 0); \
        acc[m][n] = __builtin_amdgcn_mfma_f32_16x16x32_bf16(af[m][1], bff[n][1], acc[m][n], 0, 0, 0); \
      }                                                                                   \
  } while (0)

  STG(0, 0);
  STG(1, 1);
#pragma unroll 1
  for (int ktile = 0; ktile < 14; ++ktile) {
    const int cur = ktile & 1;
    VMCNT8();                 // tile `ktile` landed; tile ktile+1 (8 loads) in flight
    BAR();
    bf16x8 af[4][2], bff[4][2];
    LOAD_FRAGS(cur, af, bff);
    LGKM0();                  // my ds_reads complete (values in regs)
    __builtin_amdgcn_sched_barrier(0);
    BAR();                    // all waves done reading buf[cur] -> safe to overwrite
    STG(cur, ktile + 2);
    __builtin_amdgcn_s_setprio(1);
    DO_MFMA(af, bff);
    __builtin_amdgcn_s_setprio(0);
  }
  {  // ktile = 14 (no further prefetch; buf0 not reused)
    VMCNT8();
    BAR();
    bf16x8 af[4][2], bff[4][2];
    LOAD_FRAGS(0, af, bff);
    DO_MFMA(af, bff);
  }
  {  // ktile = 15
    VMCNT0();
    BAR();
    bf16x8 af[4][2], bff[4][2];
    LOAD_FRAGS(1, af, bff);
    DO_MFMA(af, bff);
  }
#undef STG
#undef LOAD_FRAGS
#undef DO_MFMA

  // ---- fused epilogue (per wave: 64 rows = one full chunk x one 64-col head span) ----
  const int g2 = khalf;               // C row group: row = 4*g2+i
  const int ocol = lane & 15;         // C col within 16-block
  const int col0 = colBase + wc * 64; // this wave's 64-col span = one head-region
  const int region = col0 >> 10;      // 0=q 1=v 2=k
  const int h = (col0 & 1023) >> 6;
  const int r0 = rowBase + wr * 64;   // global token base of this wave (chunk-aligned)
  const int cch = r0 >> 6;            // chunk index
  float bv[4];
#pragma unroll
  for (int n = 0; n < 4; ++n) bv[n] = bias[col0 + 16 * n + ocol];

  if (region == 0) {                  // q: softmax over e (in-wave), *0.125
#pragma unroll
    for (int m = 0; m < 4; ++m) {
#pragma unroll
      for (int i = 0; i < 4; ++i) {
        float v[4];
#pragma unroll
        for (int n = 0; n < 4; ++n) v[n] = acc[m][n][i] + bv[n];
        float mx = fmaxf(fmaxf(v[0], v[1]), fmaxf(v[2], v[3]));
#pragma unroll
        for (int off = 1; off <= 8; off <<= 1) mx = fmaxf(mx, __shfl_xor(mx, off));
        float s = 0.f;
#pragma unroll
        for (int n = 0; n < 4; ++n) { v[n] = __expf(v[n] - mx); s += v[n]; }
#pragma unroll
        for (int off = 1; off <= 8; off <<= 1) s += __shfl_xor(s, off);
        float inv = 0.125f / s;
        int tok = r0 + 16 * m + 4 * g2 + i;
        unsigned short* qrow = qh + ((size_t)h * NTOK + tok) * 64;
#pragma unroll
        for (int n = 0; n < 4; ++n) qrow[16 * n + ocol] = f2bf(v[n] * inv);
      }
    }
  } else if (region == 1) {           // v: write transposed vt[h][c][e][tok]
    unsigned short* vb = vt + (size_t)(h * NCH + cch) * 4096;
#pragma unroll
    for (int m = 0; m < 4; ++m) {
      int tl = 16 * m + 4 * g2;
#pragma unroll
      for (int n = 0; n < 4; ++n) {
        int e = 16 * n + ocol;
        ushort4 p = { f2bf(acc[m][n][0] + bv[n]), f2bf(acc[m][n][1] + bv[n]),
                      f2bf(acc[m][n][2] + bv[n]), f2bf(acc[m][n][3] + bv[n]) };
        *(ushort4*)&vb[(size_t)e * 64 + tl] = p;
      }
    }
  } else {                            // k: exp, write kh row-major + kt transposed
    unsigned short* kb = kt + (size_t)(h * NCH + cch) * 4096;
#pragma unroll
    for (int m = 0; m < 4; ++m) {
      int tl = 16 * m + 4 * g2;
#pragma unroll
      for (int n = 0; n < 4; ++n) {
        int e = 16 * n + ocol;
        float kv[4];
#pragma unroll
        for (int i = 0; i < 4; ++i) kv[i] = __expf(acc[m][n][i] + bv[n]);
        ushort4 p = { f2bf(kv[0]), f2bf(kv[1]), f2bf(kv[2]), f2bf(kv[3]) };
        *(ushort4*)&kb[(size_t)e * 64 + tl] = p;
#pragma unroll
        for (int i = 0; i < 4; ++i)
          kh[((size_t)h * NTOK + r0 + tl + i) * 64 + e] = p[i];
      }
    }
  }
}

// ---- per-(h,c) chunk sums via MFMA: stored as ScT[e'][d]; z[d] ----
__global__ __launch_bounds__(256) void k_chunk_sums(const unsigned short* __restrict__ kt,
                                                    const unsigned short* __restrict__ vt,
                                                    float* __restrict__ Sc,
                                                    float* __restrict__ zc) {
  int h = blockIdx.x >> 5, c = blockIdx.x & 31;
  __shared__ __align__(16) unsigned short Kt[64][72], Vt[64][72];
  int t = threadIdx.x, lane = t & 63, w = t >> 6;
  int fr = lane & 15, g = lane >> 4, fko = g * 8;
  const unsigned short* kg = kt + (size_t)(h * NCH + c) * 4096;
  const unsigned short* vg = vt + (size_t)(h * NCH + c) * 4096;
  for (int s = t; s < 512; s += 256) {
    int r = s >> 3, c8 = (s & 7) * 8;
    *(ushort8v*)&Kt[r][c8] = *(const ushort8v*)&kg[r * 64 + c8];
    *(ushort8v*)&Vt[r][c8] = *(const ushort8v*)&vg[r * 64 + c8];
  }
  __syncthreads();
  bf16x8 ka[2];
#pragma unroll
  for (int ks = 0; ks < 2; ++ks) ka[ks] = *(const bf16x8*)&Kt[16 * w + fr][32 * ks + fko];
  f32x4 s4[4] = {};
#pragma unroll
  for (int nb = 0; nb < 4; ++nb)
#pragma unroll
    for (int ks = 0; ks < 2; ++ks) {
      bf16x8 vf = *(const bf16x8*)&Vt[16 * nb + fr][32 * ks + fko];
      s4[nb] = __builtin_amdgcn_mfma_f32_16x16x32_bf16(ka[ks], vf, s4[nb], 0, 0, 0);
    }
  float* so = Sc + (size_t)(h * NCH + c) * 4096;   // [e'][d]
#pragma unroll
  for (int nb = 0; nb < 4; ++nb) {
    float4 o = { s4[nb][0], s4[nb][1], s4[nb][2], s4[nb][3] };
    *(float4*)&so[(size_t)(16 * nb + fr) * 64 + 16 * w + 4 * g] = o;
  }
  if (w == 0) {
    float z = 0.f;
#pragma unroll
    for (int j = 0; j < 8; ++j) {
      bf16x8 kv = *(const bf16x8*)&Kt[lane][j * 8];
#pragma unroll
      for (int e = 0; e < 8; ++e) z += bf2f((unsigned short)kv[e]);
    }
    zc[(size_t)(h * NCH + c) * 64 + lane] = z;
  }
}

// ---- exclusive prefix over chunks, element-parallel; S out as bf16 ----
__global__ __launch_bounds__(256) void k_scan(const float* __restrict__ Sc,
                                              unsigned short* __restrict__ Sp,
                                              const float* __restrict__ zc,
                                              float* __restrict__ zp) {
  int b = blockIdx.x;
  if (b < 256) {
    int tg = b * 256 + threadIdx.x;
    int h = tg >> 12, e = tg & 4095;
    float run = 0.f;
    for (int c = 0; c < NCH; ++c) {
      size_t idx = (size_t)(h * NCH + c) * 4096 + e;
      float v = Sc[idx];
      Sp[idx] = f2bf(run);
      run += v;
    }
  } else {
#pragma unroll
    for (int j = 0; j < 4; ++j) {
      int s = threadIdx.x + j * 256;
      int h = s >> 6, d = s & 63;
      float run = 0.f;
      for (int c = 0; c < NCH; ++c) {
        size_t idx = (size_t)(h * NCH + c) * 64 + d;
        zp[idx] = run;
        run += zc[idx];
      }
    }
  }
}

// ---- attention: O = M(QK^T) V + Q S_prev, denom fused; all MFMA ----
__global__ __launch_bounds__(256) void k_attn(const unsigned short* __restrict__ qh,
                                              const unsigned short* __restrict__ kh,
                                              const unsigned short* __restrict__ vt,
                                              const unsigned short* __restrict__ Sp,
                                              const float* __restrict__ zp,
                                              float* __restrict__ out) {
  int h = blockIdx.x >> 5, c = blockIdx.x & 31;
  __shared__ __align__(16) unsigned short Qs[64][72], Ks[64][72], Vts[64][72], Sts[64][72], Ams[64][72];
  __shared__ float zs[64], denom[64];
  int t = threadIdx.x, lane = t & 63, w = t >> 6;
  int fr = lane & 15, g = lane >> 4, fko = g * 8;
  const unsigned short* qg = qh + ((size_t)h * NTOK + c * 64) * 64;
  const unsigned short* kg = kh + ((size_t)h * NTOK + c * 64) * 64;
  const unsigned short* vg = vt + (size_t)(h * NCH + c) * 4096;
  const unsigned short* sg = Sp + (size_t)(h * NCH + c) * 4096;
  for (int s = t; s < 512; s += 256) {
    int r = s >> 3, c8 = (s & 7) * 8;
    *(ushort8v*)&Qs[r][c8]  = *(const ushort8v*)&qg[r * 64 + c8];
    *(ushort8v*)&Ks[r][c8]  = *(const ushort8v*)&kg[r * 64 + c8];
    *(ushort8v*)&Vts[r][c8] = *(const ushort8v*)&vg[r * 64 + c8];
    *(ushort8v*)&Sts[r][c8] = *(const ushort8v*)&sg[r * 64 + c8];
  }
  if (t < 64) zs[t] = zp[(size_t)(h * NCH + c) * 64 + t];
  __syncthreads();

  // step 1: A = Q K^T
  bf16x8 qa[2];
#pragma unroll
  for (int ks = 0; ks < 2; ++ks) qa[ks] = *(const bf16x8*)&Qs[16 * w + fr][32 * ks + fko];
  f32x4 a1[4] = {};
#pragma unroll
  for (int mb = 0; mb < 4; ++mb)
#pragma unroll
    for (int ks = 0; ks < 2; ++ks) {
      bf16x8 kf = *(const bf16x8*)&Ks[16 * mb + fr][32 * ks + fko];
      a1[mb] = __builtin_amdgcn_mfma_f32_16x16x32_bf16(qa[ks], kf, a1[mb], 0, 0, 0);
    }
#pragma unroll
  for (int i = 0; i < 4; ++i) {
    int n = 16 * w + 4 * g + i;
    float rs = 0.f;
#pragma unroll
    for (int j = 0; j < 4; ++j) rs += bf2f(Qs[n][fr * 4 + j]) * zs[fr * 4 + j];
#pragma unroll
    for (int mb = 0; mb < 4; ++mb) {
      int m = 16 * mb + fr;
      float v = (m <= n) ? a1[mb][i] : 0.f;
      a1[mb][i] = v;
      rs += v;
      Ams[n][16 * mb + fr] = f2bf(v);
    }
#pragma unroll
    for (int off = 1; off <= 8; off <<= 1) rs += __shfl_xor(rs, off);
    if (fr == 0) denom[n] = rs + 1.25e-7f;   // eps * sum(q) = 1e-6 * 0.125
  }
  __syncthreads();

  // step 2: O^T[e'][n] = Vt·A + St·Q
  bf16x8 xa[4];
#pragma unroll
  for (int ks = 0; ks < 2; ++ks) {
    xa[ks]     = *(const bf16x8*)&Vts[16 * w + fr][32 * ks + fko];
    xa[2 + ks] = *(const bf16x8*)&Sts[16 * w + fr][32 * ks + fko];
  }
  f32x4 o4[4] = {};
#pragma unroll
  for (int nb = 0; nb < 4; ++nb)
#pragma unroll
    for (int ks = 0; ks < 2; ++ks) {
      bf16x8 afr = *(const bf16x8*)&Ams[16 * nb + fr][32 * ks + fko];
      o4[nb] = __builtin_amdgcn_mfma_f32_16x16x32_bf16(xa[ks], afr, o4[nb], 0, 0, 0);
      bf16x8 qfr = *(const bf16x8*)&Qs[16 * nb + fr][32 * ks + fko];
      o4[nb] = __builtin_amdgcn_mfma_f32_16x16x32_bf16(xa[2 + ks], qfr, o4[nb], 0, 0, 0);
    }
#pragma unroll
  for (int nb = 0; nb < 4; ++nb) {
    int n = 16 * nb + fr;
    float dv = denom[n];
    float4 res = { o4[nb][0] / dv, o4[nb][1] / dv, o4[nb][2] / dv, o4[nb][3] / dv };
    *(float4*)&out[(size_t)(c * 64 + n) * 1024 + h * 64 + 16 * w + 4 * g] = res;
  }
}

extern "C" void kernel_launch(void* const* d_in, const int* in_sizes, int n_in,
                              void* d_out, int out_size, void* d_ws, size_t ws_size,
                              hipStream_t stream) {
  (void)in_sizes; (void)n_in; (void)out_size; (void)ws_size;
  const float* x = (const float*)d_in[0];
  const float* W = (const float*)d_in[1];
  const float* b = (const float*)d_in[2];
  char* ws = (char*)d_ws;

  const size_t MB = 1024 * 1024;
  unsigned short* xb = (unsigned short*)(ws + 0);        // 4 MB
  unsigned short* Wt = (unsigned short*)(ws + 4 * MB);   // 6 MB
  unsigned short* qh = (unsigned short*)(ws + 10 * MB);  // 4 MB
  unsigned short* kh = (unsigned short*)(ws + 14 * MB);  // 4 MB
  unsigned short* kt = (unsigned short*)(ws + 18 * MB);  // 4 MB
  unsigned short* vt = (unsigned short*)(ws + 22 * MB);  // 4 MB
  float*          Sc = (float*)(ws + 26 * MB);           // 8 MB
  unsigned short* Sp = (unsigned short*)(ws + 34 * MB);  // 4 MB
  float*          zc = (float*)(ws + 38 * MB);           // 128 KB
  float*          zp = (float*)(ws + 38 * MB + 131072);  // 128 KB

  k_prep_inputs<<<dim3(5120), dim3(256), 0, stream>>>(x, xb, W, Wt);
  k_gemm_fused<<<dim3(24, 16), dim3(256), 0, stream>>>(xb, Wt, b, qh, kh, kt, vt);
  k_chunk_sums<<<dim3(512), dim3(256), 0, stream>>>(kt, vt, Sc, zc);
  k_scan<<<dim3(257), dim3(256), 0, stream>>>(Sc, Sp, zc, zp);
  k_attn<<<dim3(512), dim3(256), 0, stream>>>(qh, kh, vt, Sp, zp, (float*)d_out);
}

// Round 8
// 48.407 us; speedup vs baseline: 1.0400x; 1.0400x over previous
//
#include <hip/hip_runtime.h>
#include <stdint.h>

// B=1, N=2048, D=1024, h=16, e=64; chunks of 64 tokens -> 32 chunks/head
#define NTOK 2048
#define NCH 32

typedef __attribute__((ext_vector_type(8))) short bf16x8;
typedef __attribute__((ext_vector_type(8))) unsigned short ushort8v;
typedef __attribute__((ext_vector_type(4))) float f32x4;

__device__ __forceinline__ unsigned short f2bf(float f) {
  unsigned u = __float_as_uint(f);
  u += 0x7fffu + ((u >> 16) & 1u);   // RNE
  return (unsigned short)(u >> 16);
}
__device__ __forceinline__ float bf2f(unsigned short s) {
  return __uint_as_float(((unsigned)s) << 16);
}

// ---- fused input prep: x -> bf16 (blocks 0..2047), W -> Wt bf16 transposed (blocks 2048..5119) ----
__global__ __launch_bounds__(256) void k_prep_inputs(const float* __restrict__ x,
                                                     unsigned short* __restrict__ xb,
                                                     const float* __restrict__ W,
                                                     unsigned short* __restrict__ Wt) {
  int bid = blockIdx.x;
  if (bid < 2048) {
    int i = (bid * 256 + threadIdx.x) * 4;
    float4 v = *(const float4*)(x + i);
    ushort4 o = { f2bf(v.x), f2bf(v.y), f2bf(v.z), f2bf(v.w) };
    *(ushort4*)(xb + i) = o;
  } else {
    __shared__ float tile[32][33];
    int id = bid - 2048;            // 3072 blocks: bx in [0,96), by in [0,32)
    int bx = id % 96, by = id / 96;
    int tx = threadIdx.x & 31, ty = threadIdx.x >> 5;
    int c0 = bx * 32;
    int r0 = by * 32;
#pragma unroll
    for (int j = 0; j < 32; j += 8)
      tile[ty + j][tx] = W[(size_t)(r0 + ty + j) * 3072 + c0 + tx];
    __syncthreads();
#pragma unroll
    for (int j = 0; j < 32; j += 8)
      Wt[(size_t)(c0 + ty + j) * 1024 + r0 + tx] = f2bf(tile[tx][ty + j]);
  }
}

// ---- GEMM 2048x3072, 128x128 tile, 512 thr (8 waves of 32x64), BK=64 ----
// R3 geometry (16 waves/CU at 2 blocks/CU) + R6 counted-vmcnt depth-2 loop.
// 4 global_load_lds per thread per K-tile, uniform -> vmcnt(4) steady state.
// grid (24,16) = 384 blocks, LDS 64 KB -> 2 blocks/CU.
__global__ __launch_bounds__(512, 4) void k_gemm_fused(const unsigned short* __restrict__ xb,
                                                       const unsigned short* __restrict__ wt,
                                                       const float* __restrict__ bias,
                                                       unsigned short* __restrict__ qh,
                                                       unsigned short* __restrict__ kh,
                                                       unsigned short* __restrict__ kt,
                                                       unsigned short* __restrict__ vt) {
  __shared__ __align__(16) unsigned short As[2][128][64];    // 2 x 16 KB
  __shared__ __align__(16) unsigned short Bs[2][128][64];    // 2 x 16 KB
  const int t = threadIdx.x;           // 0..511
  const int lane = t & 63;
  const int wave = t >> 6;             // 0..7
  const int wr = wave >> 1;            // 0..3 (32-row block)
  const int wc = wave & 1;             // 0..1 (64-col block)
  const int rowBase = blockIdx.y * 128;
  const int colBase = blockIdx.x * 128;
  const int fr = lane & 15;
  const int khalf = lane >> 4;         // 0..3

  // staging (R3-verified): thread t, instr i covers phys LDS bytes [i*8192 + t*16, +16)
  //   row = i*64 + (t>>3), phys slot = t&7; logical slot = phys ^ (row&7); 4 loads/thread/tile
  const int sr = t >> 3;               // 0..63
  const int ssl = (t & 7) ^ (sr & 7);  // i*64 == 0 (mod 8) -> same for both i
  const unsigned short* agB = xb + (size_t)(rowBase + sr) * 1024 + ssl * 8;
  const unsigned short* bgB = wt + (size_t)(colBase + sr) * 1024 + ssl * 8;
  char* laB = (char*)As + t * 16;
  char* lbB = (char*)Bs + t * 16;

#define STG(buf, kt0) do {                                                                \
    _Pragma("unroll")                                                                     \
    for (int i_ = 0; i_ < 2; ++i_) {                                                      \
      __builtin_amdgcn_global_load_lds(                                                   \
          (const __attribute__((address_space(1))) void*)(agB + (kt0) * 64 + i_ * 65536), \
          (__attribute__((address_space(3))) void*)(laB + (buf) * 16384 + i_ * 8192), 16, 0, 0); \
      __builtin_amdgcn_global_load_lds(                                                   \
          (const __attribute__((address_space(1))) void*)(bgB + (kt0) * 64 + i_ * 65536), \
          (__attribute__((address_space(3))) void*)(lbB + (buf) * 16384 + i_ * 8192), 16, 0, 0); \
    }                                                                                     \
  } while (0)

#define VMCNT4() asm volatile("s_waitcnt vmcnt(4)" ::: "memory")
#define VMCNT0() asm volatile("s_waitcnt vmcnt(0)" ::: "memory")
#define LGKM0()  asm volatile("s_waitcnt lgkmcnt(0)" ::: "memory")
#define BAR()    __builtin_amdgcn_s_barrier()

  f32x4 acc[2][4] = {};
  const int fs0 = khalf ^ (fr & 7);   // swizzled slot for ks=0; ks=1 is fs0^4

#define LOAD_FRAGS(cur, af, bff) do {                                                     \
    _Pragma("unroll")                                                                     \
    for (int m = 0; m < 2; ++m) {                                                         \
      const unsigned short* r = &As[cur][wr * 32 + m * 16 + fr][0];                       \
      af[m][0] = *(const bf16x8*)(r + fs0 * 8);                                           \
      af[m][1] = *(const bf16x8*)(r + (fs0 ^ 4) * 8);                                     \
    }                                                                                     \
    _Pragma("unroll")                                                                     \
    for (int n = 0; n < 4; ++n) {                                                         \
      const unsigned short* r = &Bs[cur][wc * 64 + n * 16 + fr][0];                       \
      bff[n][0] = *(const bf16x8*)(r + fs0 * 8);                                          \
      bff[n][1] = *(const bf16x8*)(r + (fs0 ^ 4) * 8);                                    \
    }                                                                                     \
  } while (0)

#define DO_MFMA(af, bff) do {                                                             \
    _Pragma("unroll")                                                                     \
    for (int m = 0; m < 2; ++m)                                                           \
      _Pragma("unroll")                                                                   \
      for (int n = 0; n < 4; ++n) {                                                       \
        acc[m][n] = __builtin_amdgcn_mfma_f32_16x16x32_bf16(af[m][0], bff[n][0], acc[m][n], 0, 0, 0); \
        acc[m][n] = __builtin_amdgcn_mfma_f32_16x16x32_bf16(af[m][1], bff[n][1], acc[m][n], 0, 0, 0); \
      }                                                                                   \
  } while (0)

  STG(0, 0);
  STG(1, 1);
#pragma unroll 1
  for (int ktile = 0; ktile < 14; ++ktile) {
    const int cur = ktile & 1;
    VMCNT4();                 // tile `ktile` landed; tile ktile+1 (4 loads) in flight
    BAR();
    bf16x8 af[2][2], bff[4][2];
    LOAD_FRAGS(cur, af, bff);
    LGKM0();                  // my ds_reads complete (values in regs)
    __builtin_amdgcn_sched_barrier(0);
    BAR();                    // all waves done reading buf[cur] -> safe to overwrite
    STG(cur, ktile + 2);
    __builtin_amdgcn_s_setprio(1);
    DO_MFMA(af, bff);
    __builtin_amdgcn_s_setprio(0);
  }
  {  // ktile = 14 (no further prefetch; buf0 not reused)
    VMCNT4();
    BAR();
    bf16x8 af[2][2], bff[4][2];
    LOAD_FRAGS(0, af, bff);
    DO_MFMA(af, bff);
  }
  {  // ktile = 15
    VMCNT0();
    BAR();
    bf16x8 af[2][2], bff[4][2];
    LOAD_FRAGS(1, af, bff);
    DO_MFMA(af, bff);
  }
#undef STG
#undef LOAD_FRAGS
#undef DO_MFMA

  // ---- fused epilogue (R4-verified: per wave 32 rows x one 64-col head span) ----
  const int g2 = khalf;               // C row group: row = 4*g2+i
  const int ocol = lane & 15;         // C col within 16-block
  const int col0 = colBase + wc * 64; // this wave's 64-col span = one head-region
  const int region = col0 >> 10;      // 0=q 1=v 2=k
  const int h = (col0 & 1023) >> 6;
  const int r0 = rowBase + wr * 32;   // global token base of this wave
  const int cch = r0 >> 6;            // chunk index
  const int lbase = (wr & 1) * 32;    // chunk-local row base
  float bv[4];
#pragma unroll
  for (int n = 0; n < 4; ++n) bv[n] = bias[col0 + 16 * n + ocol];

  if (region == 0) {                  // q: softmax over e (in-wave), *0.125
#pragma unroll
    for (int m = 0; m < 2; ++m) {
#pragma unroll
      for (int i = 0; i < 4; ++i) {
        float v[4];
#pragma unroll
        for (int n = 0; n < 4; ++n) v[n] = acc[m][n][i] + bv[n];
        float mx = fmaxf(fmaxf(v[0], v[1]), fmaxf(v[2], v[3]));
#pragma unroll
        for (int off = 1; off <= 8; off <<= 1) mx = fmaxf(mx, __shfl_xor(mx, off));
        float s = 0.f;
#pragma unroll
        for (int n = 0; n < 4; ++n) { v[n] = __expf(v[n] - mx); s += v[n]; }
#pragma unroll
        for (int off = 1; off <= 8; off <<= 1) s += __shfl_xor(s, off);
        float inv = 0.125f / s;
        int tok = r0 + 16 * m + 4 * g2 + i;
        unsigned short* qrow = qh + ((size_t)h * NTOK + tok) * 64;
#pragma unroll
        for (int n = 0; n < 4; ++n) qrow[16 * n + ocol] = f2bf(v[n] * inv);
      }
    }
  } else if (region == 1) {           // v: write transposed vt[h][c][e][tok]
    unsigned short* vb = vt + (size_t)(h * NCH + cch) * 4096;
#pragma unroll
    for (int m = 0; m < 2; ++m) {
      int tl = lbase + 16 * m + 4 * g2;
#pragma unroll
      for (int n = 0; n < 4; ++n) {
        int e = 16 * n + ocol;
        ushort4 p = { f2bf(acc[m][n][0] + bv[n]), f2bf(acc[m][n][1] + bv[n]),
                      f2bf(acc[m][n][2] + bv[n]), f2bf(acc[m][n][3] + bv[n]) };
        *(ushort4*)&vb[(size_t)e * 64 + tl] = p;
      }
    }
  } else {                            // k: exp, write kh row-major + kt transposed
    unsigned short* kb = kt + (size_t)(h * NCH + cch) * 4096;
#pragma unroll
    for (int m = 0; m < 2; ++m) {
      int tl = lbase + 16 * m + 4 * g2;
#pragma unroll
      for (int n = 0; n < 4; ++n) {
        int e = 16 * n + ocol;
        float kv[4];
#pragma unroll
        for (int i = 0; i < 4; ++i) kv[i] = __expf(acc[m][n][i] + bv[n]);
        ushort4 p = { f2bf(kv[0]), f2bf(kv[1]), f2bf(kv[2]), f2bf(kv[3]) };
        *(ushort4*)&kb[(size_t)e * 64 + tl] = p;
#pragma unroll
        for (int i = 0; i < 4; ++i)
          kh[((size_t)h * NTOK + r0 + 16 * m + 4 * g2 + i) * 64 + e] = p[i];
      }
    }
  }
}

// ---- per-(h,c) chunk sums via MFMA: stored as ScT[e'][d]; z[d] ----
__global__ __launch_bounds__(256) void k_chunk_sums(const unsigned short* __restrict__ kt,
                                                    const unsigned short* __restrict__ vt,
                                                    float* __restrict__ Sc,
                                                    float* __restrict__ zc) {
  int h = blockIdx.x >> 5, c = blockIdx.x & 31;
  __shared__ __align__(16) unsigned short Kt[64][72], Vt[64][72];
  int t = threadIdx.x, lane = t & 63, w = t >> 6;
  int fr = lane & 15, g = lane >> 4, fko = g * 8;
  const unsigned short* kg = kt + (size_t)(h * NCH + c) * 4096;
  const unsigned short* vg = vt + (size_t)(h * NCH + c) * 4096;
  for (int s = t; s < 512; s += 256) {
    int r = s >> 3, c8 = (s & 7) * 8;
    *(ushort8v*)&Kt[r][c8] = *(const ushort8v*)&kg[r * 64 + c8];
    *(ushort8v*)&Vt[r][c8] = *(const ushort8v*)&vg[r * 64 + c8];
  }
  __syncthreads();
  bf16x8 ka[2];
#pragma unroll
  for (int ks = 0; ks < 2; ++ks) ka[ks] = *(const bf16x8*)&Kt[16 * w + fr][32 * ks + fko];
  f32x4 s4[4] = {};
#pragma unroll
  for (int nb = 0; nb < 4; ++nb)
#pragma unroll
    for (int ks = 0; ks < 2; ++ks) {
      bf16x8 vf = *(const bf16x8*)&Vt[16 * nb + fr][32 * ks + fko];
      s4[nb] = __builtin_amdgcn_mfma_f32_16x16x32_bf16(ka[ks], vf, s4[nb], 0, 0, 0);
    }
  float* so = Sc + (size_t)(h * NCH + c) * 4096;   // [e'][d]
#pragma unroll
  for (int nb = 0; nb < 4; ++nb) {
    float4 o = { s4[nb][0], s4[nb][1], s4[nb][2], s4[nb][3] };
    *(float4*)&so[(size_t)(16 * nb + fr) * 64 + 16 * w + 4 * g] = o;
  }
  if (w == 0) {
    float z = 0.f;
#pragma unroll
    for (int j = 0; j < 8; ++j) {
      bf16x8 kv = *(const bf16x8*)&Kt[lane][j * 8];
#pragma unroll
      for (int e = 0; e < 8; ++e) z += bf2f((unsigned short)kv[e]);
    }
    zc[(size_t)(h * NCH + c) * 64 + lane] = z;
  }
}

// ---- exclusive prefix over chunks, element-parallel; S out as bf16 ----
__global__ __launch_bounds__(256) void k_scan(const float* __restrict__ Sc,
                                              unsigned short* __restrict__ Sp,
                                              const float* __restrict__ zc,
                                              float* __restrict__ zp) {
  int b = blockIdx.x;
  if (b < 256) {
    int tg = b * 256 + threadIdx.x;
    int h = tg >> 12, e = tg & 4095;
    float run = 0.f;
    for (int c = 0; c < NCH; ++c) {
      size_t idx = (size_t)(h * NCH + c) * 4096 + e;
      float v = Sc[idx];
      Sp[idx] = f2bf(run);
      run += v;
    }
  } else {
#pragma unroll
    for (int j = 0; j < 4; ++j) {
      int s = threadIdx.x + j * 256;
      int h = s >> 6, d = s & 63;
      float run = 0.f;
      for (int c = 0; c < NCH; ++c) {
        size_t idx = (size_t)(h * NCH + c) * 64 + d;
        zp[idx] = run;
        run += zc[idx];
      }
    }
  }
}

// ---- attention: O = M(QK^T) V + Q S_prev, denom fused; all MFMA ----
__global__ __launch_bounds__(256) void k_attn(const unsigned short* __restrict__ qh,
                                              const unsigned short* __restrict__ kh,
                                              const unsigned short* __restrict__ vt,
                                              const unsigned short* __restrict__ Sp,
                                              const float* __restrict__ zp,
                                              float* __restrict__ out) {
  int h = blockIdx.x >> 5, c = blockIdx.x & 31;
  __shared__ __align__(16) unsigned short Qs[64][72], Ks[64][72], Vts[64][72], Sts[64][72], Ams[64][72];
  __shared__ float zs[64], denom[64];
  int t = threadIdx.x, lane = t & 63, w = t >> 6;
  int fr = lane & 15, g = lane >> 4, fko = g * 8;
  const unsigned short* qg = qh + ((size_t)h * NTOK + c * 64) * 64;
  const unsigned short* kg = kh + ((size_t)h * NTOK + c * 64) * 64;
  const unsigned short* vg = vt + (size_t)(h * NCH + c) * 4096;
  const unsigned short* sg = Sp + (size_t)(h * NCH + c) * 4096;
  for (int s = t; s < 512; s += 256) {
    int r = s >> 3, c8 = (s & 7) * 8;
    *(ushort8v*)&Qs[r][c8]  = *(const ushort8v*)&qg[r * 64 + c8];
    *(ushort8v*)&Ks[r][c8]  = *(const ushort8v*)&kg[r * 64 + c8];
    *(ushort8v*)&Vts[r][c8] = *(const ushort8v*)&vg[r * 64 + c8];
    *(ushort8v*)&Sts[r][c8] = *(const ushort8v*)&sg[r * 64 + c8];
  }
  if (t < 64) zs[t] = zp[(size_t)(h * NCH + c) * 64 + t];
  __syncthreads();

  // step 1: A = Q K^T
  bf16x8 qa[2];
#pragma unroll
  for (int ks = 0; ks < 2; ++ks) qa[ks] = *(const bf16x8*)&Qs[16 * w + fr][32 * ks + fko];
  f32x4 a1[4] = {};
#pragma unroll
  for (int mb = 0; mb < 4; ++mb)
#pragma unroll
    for (int ks = 0; ks < 2; ++ks) {
      bf16x8 kf = *(const bf16x8*)&Ks[16 * mb + fr][32 * ks + fko];
      a1[mb] = __builtin_amdgcn_mfma_f32_16x16x32_bf16(qa[ks], kf, a1[mb], 0, 0, 0);
    }
#pragma unroll
  for (int i = 0; i < 4; ++i) {
    int n = 16 * w + 4 * g + i;
    float rs = 0.f;
#pragma unroll
    for (int j = 0; j < 4; ++j) rs += bf2f(Qs[n][fr * 4 + j]) * zs[fr * 4 + j];
#pragma unroll
    for (int mb = 0; mb < 4; ++mb) {
      int m = 16 * mb + fr;
      float v = (m <= n) ? a1[mb][i] : 0.f;
      a1[mb][i] = v;
      rs += v;
      Ams[n][16 * mb + fr] = f2bf(v);
    }
#pragma unroll
    for (int off = 1; off <= 8; off <<= 1) rs += __shfl_xor(rs, off);
    if (fr == 0) denom[n] = rs + 1.25e-7f;   // eps * sum(q) = 1e-6 * 0.125
  }
  __syncthreads();

  // step 2: O^T[e'][n] = Vt·A + St·Q
  bf16x8 xa[4];
#pragma unroll
  for (int ks = 0; ks < 2; ++ks) {
    xa[ks]     = *(const bf16x8*)&Vts[16 * w + fr][32 * ks + fko];
    xa[2 + ks] = *(const bf16x8*)&Sts[16 * w + fr][32 * ks + fko];
  }
  f32x4 o4[4] = {};
#pragma unroll
  for (int nb = 0; nb < 4; ++nb)
#pragma unroll
    for (int ks = 0; ks < 2; ++ks) {
      bf16x8 afr = *(const bf16x8*)&Ams[16 * nb + fr][32 * ks + fko];
      o4[nb] = __builtin_amdgcn_mfma_f32_16x16x32_bf16(xa[ks], afr, o4[nb], 0, 0, 0);
      bf16x8 qfr = *(const bf16x8*)&Qs[16 * nb + fr][32 * ks + fko];
      o4[nb] = __builtin_amdgcn_mfma_f32_16x16x32_bf16(xa[2 + ks], qfr, o4[nb], 0, 0, 0);
    }
#pragma unroll
  for (int nb = 0; nb < 4; ++nb) {
    int n = 16 * nb + fr;
    float dv = denom[n];
    float4 res = { o4[nb][0] / dv, o4[nb][1] / dv, o4[nb][2] / dv, o4[nb][3] / dv };
    *(float4*)&out[(size_t)(c * 64 + n) * 1024 + h * 64 + 16 * w + 4 * g] = res;
  }
}

extern "C" void kernel_launch(void* const* d_in, const int* in_sizes, int n_in,
                              void* d_out, int out_size, void* d_ws, size_t ws_size,
                              hipStream_t stream) {
  (void)in_sizes; (void)n_in; (void)out_size; (void)ws_size;
  const float* x = (const float*)d_in[0];
  const float* W = (const float*)d_in[1];
  const float* b = (const float*)d_in[2];
  char* ws = (char*)d_ws;

  const size_t MB = 1024 * 1024;
  unsigned short* xb = (unsigned short*)(ws + 0);        // 4 MB
  unsigned short* Wt = (unsigned short*)(ws + 4 * MB);   // 6 MB
  unsigned short* qh = (unsigned short*)(ws + 10 * MB);  // 4 MB
  unsigned short* kh = (unsigned short*)(ws + 14 * MB);  // 4 MB
  unsigned short* kt = (unsigned short*)(ws + 18 * MB);  // 4 MB
  unsigned short* vt = (unsigned short*)(ws + 22 * MB);  // 4 MB
  float*          Sc = (float*)(ws + 26 * MB);           // 8 MB
  unsigned short* Sp = (unsigned short*)(ws + 34 * MB);  // 4 MB
  float*          zc = (float*)(ws + 38 * MB);           // 128 KB
  float*          zp = (float*)(ws + 38 * MB + 131072);  // 128 KB

  k_prep_inputs<<<dim3(5120), dim3(256), 0, stream>>>(x, xb, W, Wt);
  k_gemm_fused<<<dim3(24, 16), dim3(512), 0, stream>>>(xb, Wt, b, qh, kh, kt, vt);
  k_chunk_sums<<<dim3(512), dim3(256), 0, stream>>>(kt, vt, Sc, zc);
  k_scan<<<dim3(257), dim3(256), 0, stream>>>(Sc, Sp, zc, zp);
  k_attn<<<dim3(512), dim3(256), 0, stream>>>(qh, kh, vt, Sp, zp, (float*)d_out);
}